// Round 2
// baseline (194.432 us; speedup 1.0000x reference)
//
#include <hip/hip_runtime.h>
#include <stddef.h>

#define N_NODES 10000
#define NE 320000
#define NB 32
#define SIZE1 80000
#define SIZE2 80000
#define CAP 96          // fixed CSR capacity per node; deg ~ Poisson(32), P(>96) ~ 1e-20

// d_ws layout (int offsets)
#define WS_CURSOR 0          // 10000 ints
#define WS_RECS   10000      // ulong recs[N_NODES*CAP] = 1.92M ints (byte off 40000, 8B aligned)
#define WS_XT     1930000    // bf16 xt[N_NODES][32][8] = 1.28M ints (byte 7720000, 16B aligned)
#define WS_VBF    3210000    // bf16 vbf[NE][8][8] j-major = 10.24M ints (byte 12840000, 16B aligned)

typedef short short8 __attribute__((ext_vector_type(8)));
typedef float floatx4 __attribute__((ext_vector_type(4)));
union FragU { short8 v; ushort us[8]; uint4 u4; };

__device__ inline ushort f2bf(float f) {
  union { float f; unsigned u; } c; c.f = f;
  unsigned u = c.u;
  u += 0x7fffu + ((u >> 16) & 1u);   // round-to-nearest-even
  return (ushort)(u >> 16);
}

// Build kernel, 3 independent jobs per thread/wave:
//  1) CSR scatter: atomicAdd cursor[row] -> write 8B record {e, col} (scattered 8B).
//  2) vals fp32->bf16 transpose to j-major granules vbf[e][j][i], EDGE-ID order:
//     reads are sequential strided (L3-warm), writes are 1KB-contiguous per wave
//     instruction (vs round-0's random 128B CSR-slot scatter, which cost 66us).
//  3) x fp32->bf16 transpose xt[n][b][i], LDS-free (task (n,b) = (e>>5, e&31)).
__global__ __launch_bounds__(256) void build_kernel(const float* __restrict__ x,
                                                    const float* __restrict__ vals,
                                                    const int* __restrict__ idxs,
                                                    int* __restrict__ cursor,
                                                    unsigned long long* __restrict__ recs,
                                                    ushort* __restrict__ xt,
                                                    ushort* __restrict__ vbf) {
  const int t = threadIdx.x;
  const int lane = t & 63;
  const int e = blockIdx.x * 256 + t;            // NE = 1250*256 exactly
  const int r = idxs[e];
  const int c = idxs[NE + e];
  const int pos = atomicAdd(&cursor[r], 1);
  if (pos < CAP)
    recs[(size_t)r * CAP + pos] = (unsigned long long)(unsigned)e |
                                  ((unsigned long long)(unsigned)c << 32);

  // vals transpose: wave covers its 64 edges; lane = (kk = edge subgroup, j = col).
  const int ebase = e - lane;
  const int kk = lane >> 3;
  const int j = lane & 7;
#pragma unroll
  for (int it = 0; it < 8; ++it) {
    const int k = it * 8 + kk;                   // local edge 0..63
    const float* vp = vals + (size_t)(ebase + k) * 64 + j;
    FragU f;
#pragma unroll
    for (int i = 0; i < 8; ++i) f.us[i] = f2bf(vp[i * 8]);   // column j
    *(uint4*)(vbf + (size_t)(ebase + k) * 64 + j * 8) = f.u4;
  }

  // x transpose: xt[n][b][i] bf16. NE == N_NODES*32 exactly, one task per thread.
  const int n = e >> 5;
  const int b = e & 31;
  const float* xp = x + (size_t)b * SIZE1 + n * 8;
  float4 v0 = *(const float4*)xp;
  float4 v1 = *(const float4*)(xp + 4);
  FragU f;
  f.us[0] = f2bf(v0.x); f.us[1] = f2bf(v0.y); f.us[2] = f2bf(v0.z); f.us[3] = f2bf(v0.w);
  f.us[4] = f2bf(v1.x); f.us[5] = f2bf(v1.y); f.us[6] = f2bf(v1.z); f.us[7] = f2bf(v1.w);
  *(uint4*)(xt + (size_t)n * 256 + b * 8) = f.u4;
}

// ONE WAVE PER NODE (4 nodes per 256-block). No LDS, no cross-wave reduction.
// Per 4-edge slot: quad q handles edge s*4+q; A-frags from bf16 xt (256B
// contiguous per quad), B-frag is ONE dwordx4 from vbf[eid] (pre-transposed
// j-major bf16) on lanes nn<8.
__global__ __launch_bounds__(256) void gather_mfma_kernel(const ushort* __restrict__ xt,
                                                          const ushort* __restrict__ vbf,
                                                          const float* __restrict__ bias,
                                                          const int* __restrict__ cursor,
                                                          const unsigned long long* __restrict__ recs,
                                                          float* __restrict__ out) {
  const int t = threadIdx.x;
  const int lane = t & 63;
  const int w = t >> 6;              // wave id 0..3
  const int n = blockIdx.x * 4 + w;  // node for this wave
  const int quad = lane >> 4;
  const int nn = lane & 15;
  const int deg = min(cursor[n], CAP);
  const size_t nbase = (size_t)n * CAP;

  floatx4 acc0 = {0.f, 0.f, 0.f, 0.f};
  floatx4 acc1 = {0.f, 0.f, 0.f, 0.f};

  for (int base = 0; base < deg; base += 64) {
    const int lim = min(64, deg - base);                       // edges this chunk
    const unsigned long long rv = recs[nbase + base + min(lane, lim - 1)];  // coalesced
    const int elo = (int)(unsigned)rv;                         // edge id
    const int ehi = (int)(unsigned)(rv >> 32);                 // col (x node)
    const int nslots = (lim + 3) >> 2;                         // 4-edge slots

    for (int s = 0; s < nslots; s += 2) {
      FragU alo0, ahi0, b0, alo1, ahi1, b1;
      {
        const int le = s * 4 + quad;
        const int lec = min(le, lim - 1);
        const int eid = __shfl(elo, lec);
        const int px  = __shfl(ehi, lec);
        const ushort* xr = xt + (size_t)px * 256;
        alo0.u4 = *(const uint4*)(xr + nn * 8);                // b = nn
        ahi0.u4 = *(const uint4*)(xr + 128 + nn * 8);          // b = nn+16
        b0.u4 = make_uint4(0, 0, 0, 0);
        if (nn < 8 && le < lim)
          b0.u4 = *(const uint4*)(vbf + (size_t)eid * 64 + nn * 8);
      }
      {
        const int le = (s + 1) * 4 + quad;
        const int lec = min(le, lim - 1);
        const int eid = __shfl(elo, lec);
        const int px  = __shfl(ehi, lec);
        const ushort* xr = xt + (size_t)px * 256;
        alo1.u4 = *(const uint4*)(xr + nn * 8);
        ahi1.u4 = *(const uint4*)(xr + 128 + nn * 8);
        b1.u4 = make_uint4(0, 0, 0, 0);
        if (nn < 8 && le < lim)
          b1.u4 = *(const uint4*)(vbf + (size_t)eid * 64 + nn * 8);
      }
      acc0 = __builtin_amdgcn_mfma_f32_16x16x32_bf16(alo0.v, b0.v, acc0, 0, 0, 0);
      acc1 = __builtin_amdgcn_mfma_f32_16x16x32_bf16(ahi0.v, b0.v, acc1, 0, 0, 0);
      acc0 = __builtin_amdgcn_mfma_f32_16x16x32_bf16(alo1.v, b1.v, acc0, 0, 0, 0);
      acc1 = __builtin_amdgcn_mfma_f32_16x16x32_bf16(ahi1.v, b1.v, acc1, 0, 0, 0);
    }
  }

  // C/D: col(j) = lane&15, row(b) = quad*4 + reg. Each wave writes its node.
  if (nn < 8) {
    const float bz = bias[n * 8 + nn];
#pragma unroll
    for (int r = 0; r < 4; ++r) {
      out[(size_t)(quad * 4 + r) * SIZE2 + n * 8 + nn] = acc0[r] + bz;
      out[(size_t)(16 + quad * 4 + r) * SIZE2 + n * 8 + nn] = acc1[r] + bz;
    }
  }
}

extern "C" void kernel_launch(void* const* d_in, const int* in_sizes, int n_in,
                              void* d_out, int out_size, void* d_ws, size_t ws_size,
                              hipStream_t stream) {
  const float* x    = (const float*)d_in[0];
  const float* vals = (const float*)d_in[1];
  const float* bias = (const float*)d_in[2];
  const int*   idxs = (const int*)d_in[3];
  float* out = (float*)d_out;

  int* ws = (int*)d_ws;
  int* cursor = ws + WS_CURSOR;
  unsigned long long* recs = (unsigned long long*)(ws + WS_RECS);
  ushort* xt  = (ushort*)(ws + WS_XT);
  ushort* vbf = (ushort*)(ws + WS_VBF);

  hipMemsetAsync(cursor, 0, N_NODES * sizeof(int), stream);

  build_kernel<<<NE / 256, 256, 0, stream>>>(x, vals, idxs, cursor, recs, xt, vbf);
  gather_mfma_kernel<<<N_NODES / 4, 256, 0, stream>>>(xt, vbf, bias, cursor, recs, out);
}

// Round 3
// 174.797 us; speedup vs baseline: 1.1123x; 1.1123x over previous
//
#include <hip/hip_runtime.h>
#include <stddef.h>

#define N_NODES 10000
#define NE 320000
#define NB 32
#define SIZE1 80000
#define SIZE2 80000
#define CAP 96          // fixed CSR capacity per node; deg ~ Poisson(32), P(>96) ~ 1e-20

// d_ws layout (int offsets)
#define WS_CURSOR 0          // 10000 ints
#define WS_RECS   10000      // ulong recs[N_NODES*CAP] = 1.92M ints (byte off 40000, 8B aligned)
#define WS_XT     1930000    // bf16 xt[N_NODES][32][8] = 1.28M ints (byte 7720000, 16B aligned)

typedef short short8 __attribute__((ext_vector_type(8)));
typedef float floatx4 __attribute__((ext_vector_type(4)));
union FragU { short8 v; ushort us[8]; uint4 u4; };

__device__ inline ushort f2bf(float f) {
  union { float f; unsigned u; } c; c.f = f;
  unsigned u = c.u;
  u += 0x7fffu + ((u >> 16) & 1u);   // round-to-nearest-even
  return (ushort)(u >> 16);
}

__device__ inline unsigned pack2bf(float a, float b) {
  return (unsigned)f2bf(a) | ((unsigned)f2bf(b) << 16);
}

// Build kernel (r1 structure — proven fastest):
//  1) CSR scatter: atomicAdd cursor[row] -> one 8B record {e, col} per edge.
//  2) x fp32->bf16 transpose xt[n][b][i], LDS-free (task (n,b) = (e>>5, e&31)).
// NO vals materialization: the r2 experiment showed the extra pass over vals
// costs +16us net vs converting inline in gather.
__global__ __launch_bounds__(256) void build_kernel(const float* __restrict__ x,
                                                    const int* __restrict__ idxs,
                                                    int* __restrict__ cursor,
                                                    unsigned long long* __restrict__ recs,
                                                    ushort* __restrict__ xt) {
  const int t = threadIdx.x;
  const int e = blockIdx.x * 256 + t;            // NE = 1250*256 exactly
  const int r = idxs[e];
  const int c = idxs[NE + e];
  const int pos = atomicAdd(&cursor[r], 1);
  if (pos < CAP)
    recs[(size_t)r * CAP + pos] = (unsigned long long)(unsigned)e |
                                  ((unsigned long long)(unsigned)c << 32);

  // x transpose: xt[n][b][i] bf16. NE == N_NODES*32 exactly, one task per thread.
  const int n = e >> 5;
  const int b = e & 31;
  const float* xp = x + (size_t)b * SIZE1 + n * 8;
  float4 v0 = *(const float4*)xp;
  float4 v1 = *(const float4*)(xp + 4);
  FragU f;
  f.us[0] = f2bf(v0.x); f.us[1] = f2bf(v0.y); f.us[2] = f2bf(v0.z); f.us[3] = f2bf(v0.w);
  f.us[4] = f2bf(v1.x); f.us[5] = f2bf(v1.y); f.us[6] = f2bf(v1.z); f.us[7] = f2bf(v1.w);
  *(uint4*)(xt + (size_t)n * 256 + b * 8) = f.u4;
}

// ONE WAVE PER NODE (4 nodes per 256-block). No LDS, no cross-wave reduction.
// B-fragment build per 4-edge slot is now fully coalesced: lane (quad,nn)
// loads ONE dwordx4 of vals (the wave instruction covers the slot's 4x256B =
// 1KB contiguous edge payloads), converts to 2 packed-bf16 words, then
// redistributes to the MFMA B layout (lane nn holds column j=nn, k=i
// contiguous) via 16 ds_bpermute with loop-invariant lane indices.
// Source layout after the load: lane sl=2i+(j>>2) of the quad holds
// v[e][i][4*(j>>2)..], word (j>>1)&1, half j&1.
__global__ __launch_bounds__(256) void gather_mfma_kernel(const ushort* __restrict__ xt,
                                                          const float* __restrict__ vals,
                                                          const float* __restrict__ bias,
                                                          const int* __restrict__ cursor,
                                                          const unsigned long long* __restrict__ recs,
                                                          float* __restrict__ out) {
  const int t = threadIdx.x;
  const int lane = t & 63;
  const int w = t >> 6;              // wave id 0..3
  const int n = blockIdx.x * 4 + w;  // node for this wave
  const int quad = lane >> 4;
  const int nn = lane & 15;
  const int deg = min(cursor[n], CAP);
  const size_t nbase = (size_t)n * CAP;

  // Loop-invariant shuffle geometry.
  const int laneBase = lane & 48;            // quad*16
  const int p = (nn >> 2) & 1;               // which 16B half of the edge row-pair
  const bool selW = (nn & 2) != 0;           // which packed word
  const bool selH = (nn & 1) != 0;           // which half of the word
  int sidx[8];
#pragma unroll
  for (int i = 0; i < 8; ++i) sidx[i] = laneBase | (i << 1) | p;

  floatx4 acc0 = {0.f, 0.f, 0.f, 0.f};
  floatx4 acc1 = {0.f, 0.f, 0.f, 0.f};

  for (int base = 0; base < deg; base += 64) {
    const int lim = min(64, deg - base);                       // edges this chunk
    const unsigned long long rv = recs[nbase + base + min(lane, lim - 1)];  // coalesced
    const int elo = (int)(unsigned)rv;                         // edge id
    const int ehi = (int)(unsigned)(rv >> 32);                 // col (x node)
    const int nslots = (lim + 3) >> 2;                         // 4-edge slots

    for (int s = 0; s < nslots; s += 2) {
      // --- issue all global loads for both slots first (ILP) ---
      const int le0 = s * 4 + quad;
      const int lec0 = min(le0, lim - 1);
      const int eid0 = __shfl(elo, lec0);
      const int px0  = __shfl(ehi, lec0);
      const bool ok0 = le0 < lim;
      const int le1 = (s + 1) * 4 + quad;
      const int lec1 = min(le1, lim - 1);
      const int eid1 = __shfl(elo, lec1);
      const int px1  = __shfl(ehi, lec1);
      const bool ok1 = le1 < lim;

      float4 f0 = *(const float4*)(vals + (size_t)eid0 * 64 + nn * 4);  // coalesced 1KB/slot
      float4 f1 = *(const float4*)(vals + (size_t)eid1 * 64 + nn * 4);
      const ushort* xr0 = xt + (size_t)px0 * 256;
      const ushort* xr1 = xt + (size_t)px1 * 256;
      FragU alo0, ahi0, alo1, ahi1;
      alo0.u4 = *(const uint4*)(xr0 + nn * 8);                // batch = nn
      ahi0.u4 = *(const uint4*)(xr0 + 128 + nn * 8);          // batch = nn+16
      alo1.u4 = *(const uint4*)(xr1 + nn * 8);
      ahi1.u4 = *(const uint4*)(xr1 + 128 + nn * 8);

      // --- convert + zero invalid edges (keeps B exactly 0) ---
      unsigned u00 = pack2bf(f0.x, f0.y), u01 = pack2bf(f0.z, f0.w);
      unsigned u10 = pack2bf(f1.x, f1.y), u11 = pack2bf(f1.z, f1.w);
      if (!ok0) { u00 = 0; u01 = 0; }
      if (!ok1) { u10 = 0; u11 = 0; }

      // --- in-wave transpose to B layout: lane nn <- column j=nn ---
      FragU b0, b1;
#pragma unroll
      for (int i = 0; i < 8; ++i) {
        unsigned t00 = (unsigned)__shfl((int)u00, sidx[i]);
        unsigned t01 = (unsigned)__shfl((int)u01, sidx[i]);
        unsigned w0 = selW ? t01 : t00;
        b0.us[i] = selH ? (ushort)(w0 >> 16) : (ushort)(w0 & 0xffffu);
        unsigned t10 = (unsigned)__shfl((int)u10, sidx[i]);
        unsigned t11 = (unsigned)__shfl((int)u11, sidx[i]);
        unsigned w1 = selW ? t11 : t10;
        b1.us[i] = selH ? (ushort)(w1 >> 16) : (ushort)(w1 & 0xffffu);
      }

      acc0 = __builtin_amdgcn_mfma_f32_16x16x32_bf16(alo0.v, b0.v, acc0, 0, 0, 0);
      acc1 = __builtin_amdgcn_mfma_f32_16x16x32_bf16(ahi0.v, b0.v, acc1, 0, 0, 0);
      acc0 = __builtin_amdgcn_mfma_f32_16x16x32_bf16(alo1.v, b1.v, acc0, 0, 0, 0);
      acc1 = __builtin_amdgcn_mfma_f32_16x16x32_bf16(ahi1.v, b1.v, acc1, 0, 0, 0);
    }
  }

  // C/D: col(j) = lane&15, row(b) = quad*4 + reg. Each wave writes its node.
  if (nn < 8) {
    const float bz = bias[n * 8 + nn];
#pragma unroll
    for (int r = 0; r < 4; ++r) {
      out[(size_t)(quad * 4 + r) * SIZE2 + n * 8 + nn] = acc0[r] + bz;
      out[(size_t)(16 + quad * 4 + r) * SIZE2 + n * 8 + nn] = acc1[r] + bz;
    }
  }
}

extern "C" void kernel_launch(void* const* d_in, const int* in_sizes, int n_in,
                              void* d_out, int out_size, void* d_ws, size_t ws_size,
                              hipStream_t stream) {
  const float* x    = (const float*)d_in[0];
  const float* vals = (const float*)d_in[1];
  const float* bias = (const float*)d_in[2];
  const int*   idxs = (const int*)d_in[3];
  float* out = (float*)d_out;

  int* ws = (int*)d_ws;
  int* cursor = ws + WS_CURSOR;
  unsigned long long* recs = (unsigned long long*)(ws + WS_RECS);
  ushort* xt = (ushort*)(ws + WS_XT);

  hipMemsetAsync(cursor, 0, N_NODES * sizeof(int), stream);

  build_kernel<<<NE / 256, 256, 0, stream>>>(x, idxs, cursor, recs, xt);
  gather_mfma_kernel<<<N_NODES / 4, 256, 0, stream>>>(xt, vals, bias, cursor, recs, out);
}